// Round 1
// baseline (5150.123 us; speedup 1.0000x reference)
//
#include <hip/hip_runtime.h>
#include <hip/hip_bf16.h>
#include <cstdint>
#include <cstddef>

#define LOG2E 1.44269504088896340736f

using f32x4 = __attribute__((ext_vector_type(4))) float;
using s16x8 = __attribute__((ext_vector_type(8))) short;

static __device__ __forceinline__ float bf2f(unsigned short u) {
  union { unsigned int i; float f; } v; v.i = ((unsigned int)u) << 16; return v.f;
}
static __device__ __forceinline__ unsigned short f2bf(float f) {
  union { float f; unsigned int i; } v; v.f = f;
  unsigned int r = v.i + 0x7fffu + ((v.i >> 16) & 1u);
  return (unsigned short)(r >> 16);
}
static __device__ __forceinline__ float wredmax(float v) {
  #pragma unroll
  for (int m = 32; m > 0; m >>= 1) v = fmaxf(v, __shfl_xor(v, m, 64));
  return v;
}
static __device__ __forceinline__ float wredsum(float v) {
  #pragma unroll
  for (int m = 32; m > 0; m >>= 1) v += __shfl_xor(v, m, 64);
  return v;
}

// ---------------------------------------------------------------------------
// Transform kernel: pre-scale + re-tile weights, fold constants.
//  WB1  [k>>3][e'][k&7] bf16 = 2log2e * W1[e'][k]        (k<512, hc part)
//  WBhh [k>>3][j ][k&7] bf16 = scale(j) * W_hh[j][k]     (i,f,o: -log2e; g: +2log2e)
//  W1eT [e][e'] f32 = 2log2e * W1[e'][512+e]
//  b1s  [e'] = 2log2e * b1
//  Wihs [j][o] = scale(j)*W_ih ; gbias[j] = scale(j)*(b_ih+b_hh)
//  yh2  [b][o] = y_history[b]@W_fc[o][256:320] + b_fc[o]
// ---------------------------------------------------------------------------
__global__ void ktrans(const float* __restrict__ W1, const float* __restrict__ b1,
                       const float* __restrict__ Wih_in, const float* __restrict__ bih,
                       const float* __restrict__ Whh, const float* __restrict__ bhh,
                       const float* __restrict__ Wfc, const float* __restrict__ bfc,
                       const float* __restrict__ yhist,
                       unsigned short* __restrict__ WB1, unsigned short* __restrict__ WBhh,
                       float* __restrict__ W1eT, float* __restrict__ b1s,
                       float* __restrict__ Wihs, float* __restrict__ gbias,
                       float* __restrict__ yh2)
{
  int idx = blockIdx.x * 256 + threadIdx.x;
  const float TS = 2.f * LOG2E;
  if (idx < 131072) {                       // WB1: (k,e')
    int k = idx >> 8, e = idx & 255;
    WB1[((k >> 3) * 256 + e) * 8 + (k & 7)] = f2bf(TS * W1[e * 768 + k]);
    return;
  }
  idx -= 131072;
  if (idx < 262144) {                       // WBhh: (k,j)
    int k = idx >> 10, j = idx & 1023;
    float sc = ((j >> 8) == 2) ? TS : -LOG2E;
    WBhh[((k >> 3) * 1024 + j) * 8 + (k & 7)] = f2bf(sc * Whh[j * 256 + k]);
    return;
  }
  idx -= 262144;
  if (idx < 65536) {                        // W1eT: (e,e')
    int e = idx >> 8, ep = idx & 255;
    W1eT[idx] = TS * W1[ep * 768 + 512 + e];
    return;
  }
  idx -= 65536;
  if (idx < 256) { b1s[idx] = TS * b1[idx]; return; }
  idx -= 256;
  if (idx < 2048) {                         // Wihs (j,o)
    int j = idx >> 1;
    float sc = ((j >> 8) == 2) ? TS : -LOG2E;
    Wihs[idx] = sc * Wih_in[idx];
    return;
  }
  idx -= 2048;
  if (idx < 1024) {
    int j = idx;
    float sc = ((j >> 8) == 2) ? TS : -LOG2E;
    gbias[j] = sc * (bih[j] + bhh[j]);
    return;
  }
  idx -= 1024;
  if (idx < 4096) {                         // yh2 (b,o)
    int bq = idx >> 1, o = idx & 1;
    float a = bfc[o];
    for (int t = 0; t < 64; ++t) a = fmaf(yhist[bq * 64 + t], Wfc[o * 320 + 256 + t], a);
    yh2[idx] = a;
    return;
  }
}

// ---------------------------------------------------------------------------
// Precompute kernel: P[b][ec][t][8] bf16 = 2log2e*(x[b,t,:]@W1e.T + b1)
// plus ey[b][t][0:2] = x[b,t,:]@W_fc[:, :256].T. One block per batch row b.
// x loads are block-uniform -> scalar loads; weight loads are lane-coalesced.
// ---------------------------------------------------------------------------
__global__ __launch_bounds__(256, 4) void kpre(
    const float* __restrict__ x, const float* __restrict__ W1eT,
    const float* __restrict__ b1s, const float* __restrict__ Wfc,
    unsigned short* __restrict__ P, float* __restrict__ ey)
{
  __shared__ __align__(16) unsigned short st[64 * 264];
  const int bq = blockIdx.x;
  const int tid = threadIdx.x;              // e' = tid
  float acc[64];
  const float bb1 = b1s[tid];
  #pragma unroll
  for (int r = 0; r < 64; ++r) acc[r] = bb1;
  const float* __restrict__ xb = x + (size_t)bq * 64 * 256;
  for (int e4 = 0; e4 < 64; ++e4) {
    float wv[4];
    #pragma unroll
    for (int j2 = 0; j2 < 4; ++j2) wv[j2] = W1eT[(e4 * 4 + j2) * 256 + tid];
    #pragma unroll
    for (int r = 0; r < 64; ++r) {
      #pragma unroll
      for (int j2 = 0; j2 < 4; ++j2)
        acc[r] = fmaf(wv[j2], xb[r * 256 + e4 * 4 + j2], acc[r]);
    }
  }
  #pragma unroll
  for (int r = 0; r < 64; ++r) st[r * 264 + tid] = f2bf(acc[r]);
  __syncthreads();
  // transpose-write into [ec][t][8] layout, dword-coalesced
  unsigned int* __restrict__ Pd = (unsigned int*)P;
  for (int d = tid; d < 8192; d += 256) {
    int f = d * 2;
    int ec = f >> 9, t = (f >> 3) & 63, i0 = f & 7;
    unsigned int lo = st[t * 264 + ec * 8 + i0];
    unsigned int hi = st[t * 264 + ec * 8 + i0 + 1];
    Pd[(size_t)bq * 8192 + d] = lo | (hi << 16);
  }
  // ey
  if (tid < 128) {
    int t = tid >> 1, o = tid & 1;
    float a = 0.f;
    const float* __restrict__ xr = xb + t * 256;
    const float* __restrict__ wr = Wfc + o * 320;
    #pragma unroll 4
    for (int e = 0; e < 256; ++e) a = fmaf(xr[e], wr[e], a);
    ey[((size_t)bq * 64 + t) * 2 + o] = a;
  }
}

// ---------------------------------------------------------------------------
// Recurrence kernel: 256 blocks x 8 batch rows, 8 waves, 64 steps persistent.
// ---------------------------------------------------------------------------
__global__ __launch_bounds__(512, 2) void krecur(
    const float* __restrict__ x, const float* __restrict__ w2g,
    const unsigned short* __restrict__ WB1, const unsigned short* __restrict__ WBhh,
    const float* __restrict__ Wih, const float* __restrict__ gbias,
    const float* __restrict__ yh2, const float* __restrict__ ey,
    const unsigned short* __restrict__ P,
    const float* __restrict__ Wfin, const float* __restrict__ bfin,
    float* __restrict__ out)
{
  // hcA: bf16 state in MFMA-A-fragment order: [k>>3][b][k&7], k<512 ([h|c])
  __shared__ __align__(16) unsigned short hcA[4096];
  __shared__ __align__(16) float cS[8 * 256];
  __shared__ __align__(16) float q2[8 * 256];   // q this step; ctx at the end
  __shared__ __align__(16) float scA[8 * 64];   // alpha
  __shared__ float yt[16];
  __shared__ __align__(16) float gl[8 * 1024];  // gates; h(f32) stash at s=63
  __shared__ __align__(16) float w2s[256];

  const int tid = threadIdx.x;
  const int w = tid >> 6, lane = tid & 63;
  const int bb = blockIdx.x;                // rows bb*8 .. bb*8+7
  const int b = w;                          // wave-per-row mapping
  const int gb_row = bb * 8 + b;

  for (int i = tid; i < 4096; i += 512) hcA[i] = 0;
  for (int i = tid; i < 2048; i += 512) cS[i] = 0.f;
  if (tid < 256) w2s[tid] = w2g[tid];
  __syncthreads();

  const int frow = lane & 7;    // A-frag row (rows 8..15 duplicated, ignored)
  const int fgrp = lane >> 4;   // k-group
  const int fcol = lane & 15;   // B/D col
  const int drow0 = fgrp * 4;   // D row base

  s16x8 afr[16];

  for (int s = 0; s < 64; ++s) {
    // ---- load A fragments (hc state, bf16) ----
    #pragma unroll
    for (int kb = 0; kb < 16; ++kb)
      afr[kb] = *(const s16x8*)&hcA[((kb * 4 + fgrp) * 8 + frow) * 8];

    // ---- Q phase: q2 = hc @ W1hc_s^T  (2 N-tiles per wave) ----
    #pragma unroll
    for (int et2 = 0; et2 < 2; ++et2) {
      const int eb = (w * 2 + et2) * 16;
      f32x4 acc = {0.f, 0.f, 0.f, 0.f};
      #pragma unroll
      for (int kb = 0; kb < 16; ++kb) {
        s16x8 bfr = *(const s16x8*)&WB1[(size_t)((kb * 4 + fgrp) * 256 + eb + fcol) * 8];
        acc = __builtin_amdgcn_mfma_f32_16x16x32_bf16(afr[kb], bfr, acc, 0, 0, 0);
      }
      if (lane < 32) {
        #pragma unroll
        for (int r = 0; r < 4; ++r) q2[(drow0 + r) * 256 + eb + fcol] = acc[r];
      }
    }
    __syncthreads();

    // ---- scores + softmax + ytilde (wave = batch row, lane = t) ----
    {
      float a0 = 0.f, a1 = 0.f, a2 = 0.f, a3 = 0.f;
      const unsigned short* __restrict__ Pb = P + (size_t)gb_row * 16384;
      #pragma unroll 4
      for (int ec = 0; ec < 32; ++ec) {
        s16x8 pv = *(const s16x8*)(Pb + (size_t)(ec * 64 + lane) * 8);
        const float4* qp = (const float4*)(q2 + b * 256 + ec * 8);
        const float4* wp = (const float4*)(w2s + ec * 8);
        float4 qa = qp[0], qb = qp[1], wa = wp[0], wb = wp[1];
        a0 = fmaf(wa.x, __builtin_amdgcn_rcpf(1.f + __builtin_amdgcn_exp2f(bf2f((unsigned short)pv[0]) + qa.x)), a0);
        a1 = fmaf(wa.y, __builtin_amdgcn_rcpf(1.f + __builtin_amdgcn_exp2f(bf2f((unsigned short)pv[1]) + qa.y)), a1);
        a2 = fmaf(wa.z, __builtin_amdgcn_rcpf(1.f + __builtin_amdgcn_exp2f(bf2f((unsigned short)pv[2]) + qa.z)), a2);
        a3 = fmaf(wa.w, __builtin_amdgcn_rcpf(1.f + __builtin_amdgcn_exp2f(bf2f((unsigned short)pv[3]) + qa.w)), a3);
        a0 = fmaf(wb.x, __builtin_amdgcn_rcpf(1.f + __builtin_amdgcn_exp2f(bf2f((unsigned short)pv[4]) + qb.x)), a0);
        a1 = fmaf(wb.y, __builtin_amdgcn_rcpf(1.f + __builtin_amdgcn_exp2f(bf2f((unsigned short)pv[5]) + qb.y)), a1);
        a2 = fmaf(wb.z, __builtin_amdgcn_rcpf(1.f + __builtin_amdgcn_exp2f(bf2f((unsigned short)pv[6]) + qb.z)), a2);
        a3 = fmaf(wb.w, __builtin_amdgcn_rcpf(1.f + __builtin_amdgcn_exp2f(bf2f((unsigned short)pv[7]) + qb.w)), a3);
      }
      // s' = -2*sum(w2*r); additive consts (sum(w2)+b2) dropped: softmax-invariant
      float sc = -2.f * ((a0 + a1) + (a2 + a3));
      float mx = wredmax(sc);
      float e_t = __builtin_amdgcn_exp2f((sc - mx) * LOG2E);
      float sm = wredsum(e_t);
      float alpha = e_t * __builtin_amdgcn_rcpf(sm);
      scA[b * 64 + lane] = alpha;
      const float2 eyv = *(const float2*)&ey[((size_t)gb_row * 64 + lane) * 2];
      float y0 = wredsum(alpha * eyv.x);
      float y1 = wredsum(alpha * eyv.y);
      if (lane == 0) {
        yt[b * 2 + 0] = y0 + yh2[gb_row * 2 + 0];
        yt[b * 2 + 1] = y1 + yh2[gb_row * 2 + 1];
      }
    }
    __syncthreads();

    // ---- gates = scale*(ytilde@W_ih.T + b_ih + h@W_hh.T + b_hh)  (8 tiles/wave) ----
    #pragma unroll
    for (int jt8 = 0; jt8 < 8; ++jt8) {
      const int jb = (w * 8 + jt8) * 16;
      const int j = jb + fcol;
      const float wi0 = Wih[j * 2], wi1 = Wih[j * 2 + 1], gbj = gbias[j];
      f32x4 acc;
      #pragma unroll
      for (int r = 0; r < 4; ++r) {
        const int br = (drow0 + r) & 7;
        acc[r] = fmaf(wi0, yt[br * 2], fmaf(wi1, yt[br * 2 + 1], gbj));
      }
      #pragma unroll
      for (int kb = 0; kb < 8; ++kb) {
        s16x8 bfr = *(const s16x8*)&WBhh[(size_t)((kb * 4 + fgrp) * 1024 + j) * 8];
        acc = __builtin_amdgcn_mfma_f32_16x16x32_bf16(afr[kb], bfr, acc, 0, 0, 0);
      }
      if (lane < 32) {
        #pragma unroll
        for (int r = 0; r < 4; ++r) gl[(drow0 + r) * 1024 + j] = acc[r];
      }
    }
    __syncthreads();

    // ---- LSTM pointwise (thread owns b=w, jj = lane*4..+3) ----
    {
      const int jj0 = lane * 4;
      float hv[4], cv[4];
      #pragma unroll
      for (int i2 = 0; i2 < 4; ++i2) {
        const int jj = jj0 + i2;
        const float gi = gl[b * 1024 + jj];
        const float gf = gl[b * 1024 + 256 + jj];
        const float gg = gl[b * 1024 + 512 + jj];
        const float go = gl[b * 1024 + 768 + jj];
        const float si = __builtin_amdgcn_rcpf(1.f + __builtin_amdgcn_exp2f(gi));
        const float sf = __builtin_amdgcn_rcpf(1.f + __builtin_amdgcn_exp2f(gf));
        const float tg = 1.f - 2.f * __builtin_amdgcn_rcpf(1.f + __builtin_amdgcn_exp2f(gg));
        const float so = __builtin_amdgcn_rcpf(1.f + __builtin_amdgcn_exp2f(go));
        const float cn = sf * cS[b * 256 + jj] + si * tg;
        const float th = 1.f - 2.f * __builtin_amdgcn_rcpf(1.f + __builtin_amdgcn_exp2f(2.f * LOG2E * cn));
        const float hn = so * th;
        cS[b * 256 + jj] = cn;
        cv[i2] = cn; hv[i2] = hn;
        if (s == 63) gl[b * 1024 + jj] = hn;   // f32 h stash for final matmul
      }
      unsigned int h01 = (unsigned int)f2bf(hv[0]) | ((unsigned int)f2bf(hv[1]) << 16);
      unsigned int h23 = (unsigned int)f2bf(hv[2]) | ((unsigned int)f2bf(hv[3]) << 16);
      unsigned int c01 = (unsigned int)f2bf(cv[0]) | ((unsigned int)f2bf(cv[1]) << 16);
      unsigned int c23 = (unsigned int)f2bf(cv[2]) | ((unsigned int)f2bf(cv[3]) << 16);
      const int hk = ((jj0 >> 3) * 8 + b) * 8 + (jj0 & 7);
      const int ck = ((((256 + jj0) >> 3)) * 8 + b) * 8 + (jj0 & 7);
      *(uint2*)&hcA[hk] = make_uint2(h01, h23);
      *(uint2*)&hcA[ck] = make_uint2(c01, c23);
    }
    __syncthreads();

    if (s == 63) {   // full ctx (into q2 buffer): ctx[b][e] = sum_t alpha_t * x[b,t,e]
      #pragma unroll
      for (int p = 0; p < 4; ++p) {
        const int e = p * 64 + lane;
        float a = 0.f;
        const float* __restrict__ xr = x + (size_t)gb_row * 64 * 256 + e;
        #pragma unroll 8
        for (int t = 0; t < 64; ++t) a = fmaf(scA[b * 64 + t], xr[t * 256], a);
        q2[b * 256 + e] = a;
      }
      __syncthreads();
    }
  }

  // ---- final: out = [h, ctx] @ W_final.T + b_final ----
  {
    float o0 = 0.f, o1 = 0.f;
    #pragma unroll
    for (int kk = 0; kk < 8; ++kk) {
      const int k = kk * 64 + lane;
      const float v = (k < 256) ? gl[b * 1024 + k] : q2[b * 256 + k - 256];
      o0 = fmaf(v, Wfin[k], o0);
      o1 = fmaf(v, Wfin[512 + k], o1);
    }
    o0 = wredsum(o0);
    o1 = wredsum(o1);
    if (lane == 0) {
      out[gb_row * 2 + 0] = o0 + bfin[0];
      out[gb_row * 2 + 1] = o1 + bfin[1];
    }
  }
}

// ---------------------------------------------------------------------------
extern "C" void kernel_launch(void* const* d_in, const int* in_sizes, int n_in,
                              void* d_out, int out_size, void* d_ws, size_t ws_size,
                              hipStream_t stream) {
  const float* x    = (const float*)d_in[0];
  const float* yh   = (const float*)d_in[1];
  const float* W1   = (const float*)d_in[2];
  const float* b1   = (const float*)d_in[3];
  const float* w2   = (const float*)d_in[4];
  // d_in[5] = b2: additive constant on scores, softmax-invariant -> unused
  const float* Wih  = (const float*)d_in[6];
  const float* bih  = (const float*)d_in[7];
  const float* Whh  = (const float*)d_in[8];
  const float* bhh  = (const float*)d_in[9];
  const float* Wfc  = (const float*)d_in[10];
  const float* bfc  = (const float*)d_in[11];
  const float* Wfin = (const float*)d_in[12];
  const float* bfin = (const float*)d_in[13];

  char* ws = (char*)d_ws;
  unsigned short* P    = (unsigned short*)(ws + 0);          // 67,108,864 B
  unsigned short* WB1  = (unsigned short*)(ws + 67108864);   //    262,144 B
  unsigned short* WBhh = (unsigned short*)(ws + 67371008);   //    524,288 B
  float* W1eT  = (float*)(ws + 67895296);                    //    262,144 B
  float* b1s   = (float*)(ws + 68157440);                    //      1,024 B
  float* Wihs  = (float*)(ws + 68158464);                    //      8,192 B
  float* gbias = (float*)(ws + 68166656);                    //      4,096 B
  float* yh2   = (float*)(ws + 68170752);                    //     16,384 B
  float* ey    = (float*)(ws + 68187136);                    //  1,048,576 B -> 69,235,712 total

  ktrans<<<1821, 256, 0, stream>>>(W1, b1, Wih, bih, Whh, bhh, Wfc, bfc, yh,
                                   WB1, WBhh, W1eT, b1s, Wihs, gbias, yh2);
  kpre<<<2048, 256, 0, stream>>>(x, W1eT, b1s, Wfc, P, ey);
  krecur<<<256, 512, 0, stream>>>(x, w2, WB1, WBhh, Wihs, gbias, yh2, ey, P,
                                  Wfin, bfin, (float*)d_out);
}